// Round 4
// baseline (9965.459 us; speedup 1.0000x reference)
//
#include <hip/hip_runtime.h>
#include <hip/hip_bf16.h>

#define N_NODES 200000
#define N_EDGES 12800000
#define DIM 128

#define NBUCK 1563                    // ceil(N_NODES / 128): 128-row buckets
#define BINWG 160                     // binning workgroups
#define CH    80000                   // edges per binning wg (BINWG*CH == N_EDGES)
#define N2    (NBUCK * BINWG)         // 250080 (2-D histogram size)
#define SCAN_NBLK ((N2 + 255) / 256)  // 977

typedef float f32x2 __attribute__((ext_vector_type(2)));
typedef float f32x4 __attribute__((ext_vector_type(4)));
typedef __bf16 bf16x8 __attribute__((ext_vector_type(8)));

// ===========================================================================
// ego f32 -> packed bf16 PAIRS with dim pairing {l, l+64} (so the LDS-atomic
// accumulate is 2-way bank-aliased = free, instead of 4-way for {2l,2l+1}).
// egob2[col*64 + l] = bf16(ego[col][l]) | bf16(ego[col][l+64]) << 16
// ===========================================================================
__global__ __launch_bounds__(256) void cast_kernel(
    const float* __restrict__ ego, unsigned int* __restrict__ egob2)
{
    const int total = N_NODES * 64;
    int i = blockIdx.x * blockDim.x + threadIdx.x;
    const int stride = gridDim.x * blockDim.x;
    for (; i < total; i += stride) {
        const int col = i >> 6, l = i & 63;
        unsigned ux = __float_as_uint(ego[(size_t)col * DIM + l]);
        unsigned uy = __float_as_uint(ego[(size_t)col * DIM + l + 64]);
        ux = (ux + 0x7fffu + ((ux >> 16) & 1u)) >> 16;   // RNE to bf16
        uy = (uy + 0x7fffu + ((uy >> 16) & 1u)) >> 16;
        egob2[i] = ux | (uy << 16);
    }
}

// ===========================================================================
// 2-D bucket histogram: h2[b*BINWG + g] = #edges of bucket b in wg g's chunk.
// LDS histogram per wg (no global atomics on the hot path).
// ===========================================================================
__global__ __launch_bounds__(256) void hist2d_kernel(
    const int* __restrict__ erow, int* __restrict__ h2)
{
    __shared__ int lh[NBUCK];
    for (int k = threadIdx.x; k < NBUCK; k += 256) lh[k] = 0;
    __syncthreads();
    const int g = blockIdx.x;
    const int4* p = (const int4*)(erow + (size_t)g * CH);
    for (int k = threadIdx.x; k < CH / 4; k += 256) {
        const int4 r = p[k];
        atomicAdd(&lh[r.x >> 7], 1);
        atomicAdd(&lh[r.y >> 7], 1);
        atomicAdd(&lh[r.z >> 7], 1);
        atomicAdd(&lh[r.w >> 7], 1);
    }
    __syncthreads();
    for (int k = threadIdx.x; k < NBUCK; k += 256) h2[k * BINWG + g] = lh[k];
}

// --- 3-kernel exclusive scan of h2[0..n) -> s2 ---
__global__ __launch_bounds__(256) void scan_reduce(
    const int* __restrict__ cnt, int* __restrict__ bsum, int n)
{
    __shared__ int lds[256];
    const int idx = blockIdx.x * 256 + threadIdx.x;
    lds[threadIdx.x] = (idx < n) ? cnt[idx] : 0;
    __syncthreads();
    for (int off = 128; off > 0; off >>= 1) {
        if (threadIdx.x < off) lds[threadIdx.x] += lds[threadIdx.x + off];
        __syncthreads();
    }
    if (threadIdx.x == 0) bsum[blockIdx.x] = lds[0];
}

__global__ __launch_bounds__(1024) void scan_top(
    const int* __restrict__ bsum, int* __restrict__ bpre, int nblk)
{
    __shared__ int lds[1024];
    const int t = threadIdx.x;
    const int v = (t < nblk) ? bsum[t] : 0;
    lds[t] = v;
    __syncthreads();
    for (int off = 1; off < 1024; off <<= 1) {
        const int add = (t >= off) ? lds[t - off] : 0;
        __syncthreads();
        lds[t] += add;
        __syncthreads();
    }
    if (t < nblk) bpre[t] = lds[t] - v;
}

__global__ __launch_bounds__(256) void scan_local(
    const int* __restrict__ cnt, const int* __restrict__ bpre,
    int* __restrict__ s2, int n)
{
    __shared__ int lds[256];
    const int t = threadIdx.x;
    const int idx = blockIdx.x * 256 + t;
    const int v = (idx < n) ? cnt[idx] : 0;
    lds[t] = v;
    __syncthreads();
    for (int off = 1; off < 256; off <<= 1) {
        const int add = (t >= off) ? lds[t - off] : 0;
        __syncthreads();
        lds[t] += add;
        __syncthreads();
    }
    if (idx < n) s2[idx] = lds[t] - v + bpre[blockIdx.x];
}

// ===========================================================================
// Binning scatter: wg g writes its chunk's edges into private sub-regions
// [s2[b*BINWG+g] ...) per bucket — each 64 B destination line is owned by
// exactly one wg and stays L2-resident until full (writes ~= payload).
// Entry: {lo = col<<14 | val_q14, hi = row & 127}
// ===========================================================================
__global__ __launch_bounds__(256) void bin_kernel(
    const int* __restrict__ erow, const int* __restrict__ ecol,
    const float* __restrict__ eval, const int* __restrict__ s2,
    uint2* __restrict__ sorted)
{
    __shared__ int cur[NBUCK];
    const int g = blockIdx.x;
    for (int k = threadIdx.x; k < NBUCK; k += 256) cur[k] = s2[k * BINWG + g];
    __syncthreads();
    const int4*   pr = (const int4*)(erow + (size_t)g * CH);
    const int4*   pc = (const int4*)(ecol + (size_t)g * CH);
    const float4* pv = (const float4*)(eval + (size_t)g * CH);
    for (int k = threadIdx.x; k < CH / 4; k += 256) {
        const int4 r = pr[k];
        const int4 c = pc[k];
        const float4 v = pv[k];
        {
            const int pos = atomicAdd(&cur[r.x >> 7], 1);
            const unsigned q = (unsigned)__float2int_rn(v.x * 16383.0f);
            sorted[pos] = make_uint2(((unsigned)c.x << 14) | q, (unsigned)(r.x & 127));
        }
        {
            const int pos = atomicAdd(&cur[r.y >> 7], 1);
            const unsigned q = (unsigned)__float2int_rn(v.y * 16383.0f);
            sorted[pos] = make_uint2(((unsigned)c.y << 14) | q, (unsigned)(r.y & 127));
        }
        {
            const int pos = atomicAdd(&cur[r.z >> 7], 1);
            const unsigned q = (unsigned)__float2int_rn(v.z * 16383.0f);
            sorted[pos] = make_uint2(((unsigned)c.z << 14) | q, (unsigned)(r.z & 127));
        }
        {
            const int pos = atomicAdd(&cur[r.w >> 7], 1);
            const unsigned q = (unsigned)__float2int_rn(v.w * 16383.0f);
            sorted[pos] = make_uint2(((unsigned)c.w << 14) | q, (unsigned)(r.w & 127));
        }
    }
}

// ===========================================================================
// Bucket accumulate: one 512-thread wg per 128-row bucket; 64 KB LDS f32
// accumulators; wave-per-edge readlane broadcast; lane l owns dims {l, l+64}
// (2-way bank-aliased ds_add_f32 = free); coalesced 64 KB writeout.
// ===========================================================================
__global__ __launch_bounds__(512) void accum_kernel(
    const int* __restrict__ s2, const uint2* __restrict__ sorted,
    const unsigned int* __restrict__ egob2, float* __restrict__ side)
{
    __shared__ float acc[128 * DIM];   // 64 KB
    const int b = blockIdx.x;
    for (int k = threadIdx.x; k < 128 * DIM; k += 512) acc[k] = 0.0f;
    __syncthreads();

    const int s = s2[b * BINWG];
    const int e = (b == NBUCK - 1) ? N_EDGES : s2[(b + 1) * BINWG];
    const int lane = threadIdx.x & 63;
    const int w    = threadIdx.x >> 6;   // 0..7
    const float qs = 1.0f / 16383.0f;

    for (int gb = s + w * 64; gb < e; gb += 8 * 64) {
        const int m = e - gb;
        const int cnt = (m < 64) ? m : 64;
        uint2 ev = make_uint2(0u, 0u);
        if (lane < cnt) ev = sorted[gb + lane];
        int j = 0;
        for (; j + 8 <= cnt; j += 8) {
            unsigned lo[8], hi[8], dd[8];
            #pragma unroll
            for (int u = 0; u < 8; ++u) {
                lo[u] = __builtin_amdgcn_readlane(ev.x, j + u);
                hi[u] = __builtin_amdgcn_readlane(ev.y, j + u);
            }
            #pragma unroll
            for (int u = 0; u < 8; ++u)
                dd[u] = egob2[(size_t)(lo[u] >> 14) * 64 + lane];
            #pragma unroll
            for (int u = 0; u < 8; ++u) {
                const float vv = (float)(lo[u] & 16383u) * qs;
                float* row = &acc[hi[u] * DIM + lane];
                atomicAdd(row,      vv * __uint_as_float(dd[u] << 16));
                atomicAdd(row + 64, vv * __uint_as_float(dd[u] & 0xffff0000u));
            }
        }
        for (; j < cnt; ++j) {
            const unsigned lj = __builtin_amdgcn_readlane(ev.x, j);
            const unsigned hj = __builtin_amdgcn_readlane(ev.y, j);
            const unsigned dj = egob2[(size_t)(lj >> 14) * 64 + lane];
            const float vj = (float)(lj & 16383u) * qs;
            float* row = &acc[hj * DIM + lane];
            atomicAdd(row,      vj * __uint_as_float(dj << 16));
            atomicAdd(row + 64, vj * __uint_as_float(dj & 0xffff0000u));
        }
    }
    __syncthreads();

    const int R0 = b * 128;
    const f32x4* av = (const f32x4*)acc;
    for (int k = threadIdx.x; k < 128 * (DIM / 4); k += 512) {
        const int R = R0 + (k >> 5);
        if (R < N_NODES)
            ((f32x4*)side)[(size_t)R * (DIM / 4) + (k & 31)] = av[k];
    }
}

// ---------------------------------------------------------------------------
// Fallback scatter (atomics) — used only if ws is too small for CSR.
// ---------------------------------------------------------------------------
__global__ __launch_bounds__(256) void scatter_kernel(
    const int* __restrict__ erow, const int* __restrict__ ecol,
    const float* __restrict__ eval, const float* __restrict__ ego,
    float* __restrict__ side)
{
    const int lane   = threadIdx.x & 63;
    const int wave   = blockIdx.x * (blockDim.x >> 6) + (threadIdx.x >> 6);
    const int nwaves = gridDim.x * (blockDim.x >> 6);
    const int ngroups = N_EDGES / 64;

    for (int g = wave; g < ngroups; g += nwaves) {
        const int e = g * 64 + lane;
        const int r = erow[e];
        const int c = ecol[e];
        const float v = eval[e];
        #pragma unroll 4
        for (int j = 0; j < 64; ++j) {
            const int rj = __builtin_amdgcn_readlane(r, j);
            const int cj = __builtin_amdgcn_readlane(c, j);
            const float vj = __int_as_float(__builtin_amdgcn_readlane(__float_as_int(v), j));
            const f32x2 gv = ((const f32x2*)(ego + (size_t)cj * DIM))[lane];
            float* dst = side + (size_t)rj * DIM + lane * 2;
            unsafeAtomicAdd(dst,     vj * gv.x);
            unsafeAtomicAdd(dst + 1, vj * gv.y);
        }
    }
}

// ---------------------------------------------------------------------------
// Phase 2: out = lrelu((ego+side)@W1 + b1) + lrelu((ego*side)@W2 + b2)
// bf16 MFMA 16x16x32, W^T in swizzled LDS.
// ---------------------------------------------------------------------------
__device__ __forceinline__ int swz(int c, int k) {
    return c * DIM + ((((k >> 3) ^ (c & 7)) << 3) | (k & 7));
}

__global__ __launch_bounds__(256) void dense_kernel(
    const float* __restrict__ ego, const float* side_in,
    const float* __restrict__ W1, const float* __restrict__ b1,
    const float* __restrict__ W2, const float* __restrict__ b2,
    float* out)
{
    __shared__ __bf16 w1t[DIM * DIM];
    __shared__ __bf16 w2t[DIM * DIM];

    for (int idx = threadIdx.x; idx < DIM * DIM; idx += blockDim.x) {
        const int k = idx >> 7, c = idx & 127;
        w1t[swz(c, k)] = (__bf16)W1[idx];
        w2t[swz(c, k)] = (__bf16)W2[idx];
    }
    __syncthreads();

    const int lane = threadIdx.x & 63;
    const int lrow = lane & 15;
    const int lgrp = lane >> 4;
    const int wave   = blockIdx.x * (blockDim.x >> 6) + (threadIdx.x >> 6);
    const int nwaves = gridDim.x * (blockDim.x >> 6);

    float b1v[8], b2v[8];
    #pragma unroll
    for (int ct = 0; ct < 8; ++ct) {
        b1v[ct] = b1[ct * 16 + lrow];
        b2v[ct] = b2[ct * 16 + lrow];
    }

    const int ntiles = N_NODES / 16;
    for (int t = wave; t < ntiles; t += nwaves) {
        const int node = t * 16 + lrow;
        f32x4 acc1[8], acc2[8];
        #pragma unroll
        for (int ct = 0; ct < 8; ++ct) {
            acc1[ct] = (f32x4)(0.0f);
            acc2[ct] = (f32x4)(0.0f);
        }

        #pragma unroll
        for (int ks = 0; ks < 4; ++ks) {
            const int kk = ks * 32 + lgrp * 8;
            const f32x4* ep = (const f32x4*)(ego     + (size_t)node * DIM + kk);
            const f32x4* sp = (const f32x4*)(side_in + (size_t)node * DIM + kk);
            const f32x4 e0 = ep[0], e1 = ep[1];
            const f32x4 s0 = sp[0], s1 = sp[1];
            bf16x8 ax, ay;
            #pragma unroll
            for (int j = 0; j < 4; ++j) {
                ax[j]     = (__bf16)(e0[j] + s0[j]);
                ax[j + 4] = (__bf16)(e1[j] + s1[j]);
                ay[j]     = (__bf16)(e0[j] * s0[j]);
                ay[j + 4] = (__bf16)(e1[j] * s1[j]);
            }
            #pragma unroll
            for (int ct = 0; ct < 8; ++ct) {
                const int c = ct * 16 + lrow;
                const bf16x8 bv1 = *(const bf16x8*)&w1t[swz(c, kk)];
                const bf16x8 bv2 = *(const bf16x8*)&w2t[swz(c, kk)];
                acc1[ct] = __builtin_amdgcn_mfma_f32_16x16x32_bf16(ax, bv1, acc1[ct], 0, 0, 0);
                acc2[ct] = __builtin_amdgcn_mfma_f32_16x16x32_bf16(ay, bv2, acc2[ct], 0, 0, 0);
            }
        }

        const int orow_base = t * 16 + lgrp * 4;
        #pragma unroll
        for (int ct = 0; ct < 8; ++ct) {
            #pragma unroll
            for (int j = 0; j < 4; ++j) {
                float u = acc1[ct][j] + b1v[ct];
                float w = acc2[ct][j] + b2v[ct];
                u = (u > 0.0f) ? u : 0.01f * u;
                w = (w > 0.0f) ? w : 0.01f * w;
                out[(size_t)(orow_base + j) * DIM + ct * 16 + lrow] = u + w;
            }
        }
    }
}

extern "C" void kernel_launch(void* const* d_in, const int* in_sizes, int n_in,
                              void* d_out, int out_size, void* d_ws, size_t ws_size,
                              hipStream_t stream) {
    const int*   erow = (const int*)d_in[0];
    const int*   ecol = (const int*)d_in[1];
    const float* eval = (const float*)d_in[2];
    const float* ego  = (const float*)d_in[3];
    const float* W1   = (const float*)d_in[4];
    const float* b1   = (const float*)d_in[5];
    const float* W2   = (const float*)d_in[6];
    const float* b2   = (const float*)d_in[7];
    float* out = (float*)d_out;

    // workspace layout (256B-aligned slabs)
    size_t off = 0;
    auto alloc = [&](size_t bytes) { size_t o = off; off = (off + bytes + 255) & ~(size_t)255; return o; };
    const size_t o_h2     = alloc((size_t)N2 * sizeof(int));
    const size_t o_s2     = alloc((size_t)N2 * sizeof(int));
    const size_t o_bsum   = alloc((size_t)SCAN_NBLK * sizeof(int));
    const size_t o_bpre   = alloc((size_t)SCAN_NBLK * sizeof(int));
    const size_t o_sorted = alloc((size_t)N_EDGES * sizeof(uint2));
    const size_t o_egob   = alloc((size_t)N_NODES * 64 * sizeof(unsigned int));
    const size_t need = off;

    if (ws_size >= need) {
        int*      h2     = (int*)((char*)d_ws + o_h2);
        int*      s2     = (int*)((char*)d_ws + o_s2);
        int*      bsum   = (int*)((char*)d_ws + o_bsum);
        int*      bpre   = (int*)((char*)d_ws + o_bpre);
        uint2*    sorted = (uint2*)((char*)d_ws + o_sorted);
        unsigned* egob2  = (unsigned*)((char*)d_ws + o_egob);

        cast_kernel  <<<4096, 256, 0, stream>>>(ego, egob2);
        hist2d_kernel<<<BINWG, 256, 0, stream>>>(erow, h2);
        scan_reduce  <<<SCAN_NBLK, 256, 0, stream>>>(h2, bsum, N2);
        scan_top     <<<1, 1024, 0, stream>>>(bsum, bpre, SCAN_NBLK);
        scan_local   <<<SCAN_NBLK, 256, 0, stream>>>(h2, bpre, s2, N2);
        bin_kernel   <<<BINWG, 256, 0, stream>>>(erow, ecol, eval, s2, sorted);
        accum_kernel <<<NBUCK, 512, 0, stream>>>(s2, sorted, egob2, out);
    } else {
        hipMemsetAsync(out, 0, (size_t)N_NODES * DIM * sizeof(float), stream);
        scatter_kernel<<<4096, 256, 0, stream>>>(erow, ecol, eval, ego, out);
    }
    dense_kernel<<<512, 256, 0, stream>>>(ego, out, W1, b1, W2, b2, out);
}

// Round 6
// 1280.987 us; speedup vs baseline: 7.7795x; 7.7795x over previous
//
#include <hip/hip_runtime.h>
#include <hip/hip_bf16.h>

#define N_NODES 200000
#define N_EDGES 12800000
#define DIM 128

#define NBUCK 1563                    // ceil(N_NODES / 128): 128-row buckets
#define BINWG 160                     // binning workgroups
#define CH    80000                   // edges per binning wg (BINWG*CH == N_EDGES)
#define N2    (NBUCK * BINWG)         // 250080 (2-D histogram size)
#define SCAN_NBLK ((N2 + 255) / 256)  // 977
#define CAP   7936                    // rowsort LDS stage capacity (63.5 KB)

typedef float f32x2 __attribute__((ext_vector_type(2)));
typedef float f32x4 __attribute__((ext_vector_type(4)));
typedef __bf16 bf16x8 __attribute__((ext_vector_type(8)));

// ===========================================================================
// ego f32 -> packed bf16 pairs (RNE), one dword = dims {2l, 2l+1}
// egob[col*64 + l] = bf16(ego[col][2l]) | bf16(ego[col][2l+1]) << 16
// ===========================================================================
__global__ __launch_bounds__(256) void cast_kernel(
    const float* __restrict__ ego, unsigned int* __restrict__ egob)
{
    const int total = N_NODES * 64;
    int i = blockIdx.x * blockDim.x + threadIdx.x;
    const int stride = gridDim.x * blockDim.x;
    for (; i < total; i += stride) {
        const f32x2 v = ((const f32x2*)ego)[i];
        unsigned ux = __float_as_uint(v.x), uy = __float_as_uint(v.y);
        ux = (ux + 0x7fffu + ((ux >> 16) & 1u)) >> 16;   // RNE to bf16
        uy = (uy + 0x7fffu + ((uy >> 16) & 1u)) >> 16;
        egob[i] = ux | (uy << 16);
    }
}

// ===========================================================================
// 2-D bucket histogram: h2[b*BINWG + g] = #edges of bucket b in wg g's chunk.
// ===========================================================================
__global__ __launch_bounds__(256) void hist2d_kernel(
    const int* __restrict__ erow, int* __restrict__ h2)
{
    __shared__ int lh[NBUCK];
    for (int k = threadIdx.x; k < NBUCK; k += 256) lh[k] = 0;
    __syncthreads();
    const int g = blockIdx.x;
    const int4* p = (const int4*)(erow + (size_t)g * CH);
    for (int k = threadIdx.x; k < CH / 4; k += 256) {
        const int4 r = p[k];
        atomicAdd(&lh[r.x >> 7], 1);
        atomicAdd(&lh[r.y >> 7], 1);
        atomicAdd(&lh[r.z >> 7], 1);
        atomicAdd(&lh[r.w >> 7], 1);
    }
    __syncthreads();
    for (int k = threadIdx.x; k < NBUCK; k += 256) h2[k * BINWG + g] = lh[k];
}

// --- 3-kernel exclusive scan of h2[0..n) -> s2 ---
__global__ __launch_bounds__(256) void scan_reduce(
    const int* __restrict__ cnt, int* __restrict__ bsum, int n)
{
    __shared__ int lds[256];
    const int idx = blockIdx.x * 256 + threadIdx.x;
    lds[threadIdx.x] = (idx < n) ? cnt[idx] : 0;
    __syncthreads();
    for (int off = 128; off > 0; off >>= 1) {
        if (threadIdx.x < off) lds[threadIdx.x] += lds[threadIdx.x + off];
        __syncthreads();
    }
    if (threadIdx.x == 0) bsum[blockIdx.x] = lds[0];
}

__global__ __launch_bounds__(1024) void scan_top(
    const int* __restrict__ bsum, int* __restrict__ bpre, int nblk)
{
    __shared__ int lds[1024];
    const int t = threadIdx.x;
    const int v = (t < nblk) ? bsum[t] : 0;
    lds[t] = v;
    __syncthreads();
    for (int off = 1; off < 1024; off <<= 1) {
        const int add = (t >= off) ? lds[t - off] : 0;
        __syncthreads();
        lds[t] += add;
        __syncthreads();
    }
    if (t < nblk) bpre[t] = lds[t] - v;
}

__global__ __launch_bounds__(256) void scan_local(
    const int* __restrict__ cnt, const int* __restrict__ bpre,
    int* __restrict__ s2, int n)
{
    __shared__ int lds[256];
    const int t = threadIdx.x;
    const int idx = blockIdx.x * 256 + t;
    const int v = (idx < n) ? cnt[idx] : 0;
    lds[t] = v;
    __syncthreads();
    for (int off = 1; off < 256; off <<= 1) {
        const int add = (t >= off) ? lds[t - off] : 0;
        __syncthreads();
        lds[t] += add;
        __syncthreads();
    }
    if (idx < n) s2[idx] = lds[t] - v + bpre[blockIdx.x];
}

// ===========================================================================
// Pass-1 binning: wg g writes its chunk's edges into private per-bucket
// sub-regions (L2-resident lines, written once).
// Entry: {lo = col<<14 | val_q14, hi = row & 127}
// ===========================================================================
__global__ __launch_bounds__(256) void bin_kernel(
    const int* __restrict__ erow, const int* __restrict__ ecol,
    const float* __restrict__ eval, const int* __restrict__ s2,
    uint2* __restrict__ sorted)
{
    __shared__ int cur[NBUCK];
    const int g = blockIdx.x;
    for (int k = threadIdx.x; k < NBUCK; k += 256) cur[k] = s2[k * BINWG + g];
    __syncthreads();
    const int4*   pr = (const int4*)(erow + (size_t)g * CH);
    const int4*   pc = (const int4*)(ecol + (size_t)g * CH);
    const float4* pv = (const float4*)(eval + (size_t)g * CH);
    for (int k = threadIdx.x; k < CH / 4; k += 256) {
        const int4 r = pr[k];
        const int4 c = pc[k];
        const float4 v = pv[k];
        {
            const int pos = atomicAdd(&cur[r.x >> 7], 1);
            const unsigned q = (unsigned)__float2int_rn(v.x * 16383.0f);
            sorted[pos] = make_uint2(((unsigned)c.x << 14) | q, (unsigned)(r.x & 127));
        }
        {
            const int pos = atomicAdd(&cur[r.y >> 7], 1);
            const unsigned q = (unsigned)__float2int_rn(v.y * 16383.0f);
            sorted[pos] = make_uint2(((unsigned)c.y << 14) | q, (unsigned)(r.y & 127));
        }
        {
            const int pos = atomicAdd(&cur[r.z >> 7], 1);
            const unsigned q = (unsigned)__float2int_rn(v.z * 16383.0f);
            sorted[pos] = make_uint2(((unsigned)c.z << 14) | q, (unsigned)(r.z & 127));
        }
        {
            const int pos = atomicAdd(&cur[r.w >> 7], 1);
            const unsigned q = (unsigned)__float2int_rn(v.w * 16383.0f);
            sorted[pos] = make_uint2(((unsigned)c.w << 14) | q, (unsigned)(r.w & 127));
        }
    }
}

// ===========================================================================
// Pass-2 row sort: wg per bucket.  LDS int histogram of the 128 local rows,
// LDS scan, then scatter entries IN PLACE as 4B records into the bucket's
// own byte range: out4 = ((uint*)sorted) + 2*s.  Writes cover bytes
// [8s, 8s+4*cnt); chunk-0 (<=CAP entries, covering >= cnt/2) is staged in
// LDS before any write, and chunk-1 reads start at byte 8s+8*CAP >= 8s+4*cnt
// (cnt <= 2*CAP) — no read-after-clobber.  Emits rowptr2[b*129 + r] as uint
// indices into the 4B array.  Int LDS atomics only (native).
// ===========================================================================
__global__ __launch_bounds__(256) void rowsort_kernel(
    const int* __restrict__ s2, uint2* __restrict__ sorted,
    int* __restrict__ rowptr2)
{
    __shared__ uint2 stage[CAP];
    __shared__ int h[128], sc[128], cur[128];

    const int b = blockIdx.x;
    const int s = s2[b * BINWG];
    const int e = (b == NBUCK - 1) ? N_EDGES : s2[(b + 1) * BINWG];
    const int cnt = e - s;
    const int t = threadIdx.x;

    if (t < 128) h[t] = 0;
    __syncthreads();

    unsigned* out4 = ((unsigned*)sorted) + 2 * (size_t)s;
    const int c0 = (cnt < CAP) ? cnt : CAP;

    if (cnt <= CAP) {
        // stage everything, histogram while staging
        for (int i = t; i < cnt; i += 256) {
            const uint2 v = sorted[s + i];
            stage[i] = v;
            atomicAdd(&h[v.y], 1);
        }
    } else {
        for (int i = t; i < cnt; i += 256)
            atomicAdd(&h[sorted[s + i].y], 1);
    }
    __syncthreads();

    // scan 128 (Hillis-Steele)
    int hv = 0;
    if (t < 128) { hv = h[t]; sc[t] = hv; }
    __syncthreads();
    for (int off = 1; off < 128; off <<= 1) {
        int v = 0;
        if (t >= off && t < 128) v = sc[t - off];
        __syncthreads();
        if (t < 128) sc[t] += v;
        __syncthreads();
    }
    if (t < 128) {
        const int pre = sc[t] - hv;
        cur[t] = pre;
        rowptr2[b * 129 + t] = 2 * s + pre;
    }
    if (t == 0) rowptr2[b * 129 + 128] = 2 * s + cnt;
    __syncthreads();

    if (cnt <= CAP) {
        for (int i = t; i < cnt; i += 256) {
            const uint2 v = stage[i];
            const int p = atomicAdd(&cur[v.y], 1);
            out4[p] = v.x;
        }
    } else {
        for (int i = t; i < c0; i += 256) stage[i] = sorted[s + i];
        __syncthreads();
        for (int i = t; i < c0; i += 256) {
            const uint2 v = stage[i];
            const int p = atomicAdd(&cur[v.y], 1);
            out4[p] = v.x;
        }
        __syncthreads();
        for (int i = c0 + t; i < cnt; i += 256) {
            const uint2 v = sorted[s + i];
            const int p = atomicAdd(&cur[v.y], 1);
            out4[p] = v.x;
        }
    }
}

// ===========================================================================
// Gather-side SpMM: one wave per node, register accumulate, write once.
// Entries are 4B {col<<14 | val_q14}; ego gathered as packed bf16 pairs.
// ===========================================================================
__global__ __launch_bounds__(256) void gather_kernel(
    const int* __restrict__ rowptr2, const unsigned int* __restrict__ sorted4,
    const unsigned int* __restrict__ egob, float* __restrict__ side)
{
    const int lane   = threadIdx.x & 63;
    const int wave   = blockIdx.x * (blockDim.x >> 6) + (threadIdx.x >> 6);
    const int nwaves = gridDim.x * (blockDim.x >> 6);
    const float qs = 1.0f / 16383.0f;

    for (int n = wave; n < N_NODES; n += nwaves) {
        const int rp = (n >> 7) * 129 + (n & 127);
        const int start = rowptr2[rp], end = rowptr2[rp + 1];
        float a0 = 0.0f, a1 = 0.0f;
        for (int base = start; base < end; base += 64) {
            const int m = end - base;               // wave-uniform
            const int cnt = (m < 64) ? m : 64;
            unsigned w = 0;
            if (lane < cnt) w = sorted4[base + lane];
            int j = 0;
            for (; j + 8 <= cnt; j += 8) {
                unsigned ww[8], dd[8];
                #pragma unroll
                for (int u = 0; u < 8; ++u)
                    ww[u] = __builtin_amdgcn_readlane(w, j + u);
                #pragma unroll
                for (int u = 0; u < 8; ++u)
                    dd[u] = egob[(size_t)(ww[u] >> 14) * 64 + lane];
                #pragma unroll
                for (int u = 0; u < 8; ++u) {
                    const float vv = (float)(ww[u] & 16383u) * qs;
                    a0 = fmaf(vv, __uint_as_float(dd[u] << 16), a0);
                    a1 = fmaf(vv, __uint_as_float(dd[u] & 0xffff0000u), a1);
                }
            }
            for (; j < cnt; ++j) {
                const unsigned wj = __builtin_amdgcn_readlane(w, j);
                const unsigned dj = egob[(size_t)(wj >> 14) * 64 + lane];
                const float vj = (float)(wj & 16383u) * qs;
                a0 = fmaf(vj, __uint_as_float(dj << 16), a0);
                a1 = fmaf(vj, __uint_as_float(dj & 0xffff0000u), a1);
            }
        }
        f32x2 r; r.x = a0; r.y = a1;
        ((f32x2*)(side + (size_t)n * DIM))[lane] = r;   // dims {2*lane, 2*lane+1}
    }
}

// ---------------------------------------------------------------------------
// Fallback scatter (atomics) — used only if ws is too small.
// ---------------------------------------------------------------------------
__global__ __launch_bounds__(256) void scatter_kernel(
    const int* __restrict__ erow, const int* __restrict__ ecol,
    const float* __restrict__ eval, const float* __restrict__ ego,
    float* __restrict__ side)
{
    const int lane   = threadIdx.x & 63;
    const int wave   = blockIdx.x * (blockDim.x >> 6) + (threadIdx.x >> 6);
    const int nwaves = gridDim.x * (blockDim.x >> 6);
    const int ngroups = N_EDGES / 64;

    for (int g = wave; g < ngroups; g += nwaves) {
        const int e = g * 64 + lane;
        const int r = erow[e];
        const int c = ecol[e];
        const float v = eval[e];
        #pragma unroll 4
        for (int j = 0; j < 64; ++j) {
            const int rj = __builtin_amdgcn_readlane(r, j);
            const int cj = __builtin_amdgcn_readlane(c, j);
            const float vj = __int_as_float(__builtin_amdgcn_readlane(__float_as_int(v), j));
            const f32x2 gv = ((const f32x2*)(ego + (size_t)cj * DIM))[lane];
            float* dst = side + (size_t)rj * DIM + lane * 2;
            unsafeAtomicAdd(dst,     vj * gv.x);
            unsafeAtomicAdd(dst + 1, vj * gv.y);
        }
    }
}

// ---------------------------------------------------------------------------
// Phase 2: out = lrelu((ego+side)@W1 + b1) + lrelu((ego*side)@W2 + b2)
// bf16 MFMA 16x16x32, W^T in swizzled LDS.
// ---------------------------------------------------------------------------
__device__ __forceinline__ int swz(int c, int k) {
    return c * DIM + ((((k >> 3) ^ (c & 7)) << 3) | (k & 7));
}

__global__ __launch_bounds__(256) void dense_kernel(
    const float* __restrict__ ego, const float* side_in,
    const float* __restrict__ W1, const float* __restrict__ b1,
    const float* __restrict__ W2, const float* __restrict__ b2,
    float* out)
{
    __shared__ __bf16 w1t[DIM * DIM];
    __shared__ __bf16 w2t[DIM * DIM];

    for (int idx = threadIdx.x; idx < DIM * DIM; idx += blockDim.x) {
        const int k = idx >> 7, c = idx & 127;
        w1t[swz(c, k)] = (__bf16)W1[idx];
        w2t[swz(c, k)] = (__bf16)W2[idx];
    }
    __syncthreads();

    const int lane = threadIdx.x & 63;
    const int lrow = lane & 15;
    const int lgrp = lane >> 4;
    const int wave   = blockIdx.x * (blockDim.x >> 6) + (threadIdx.x >> 6);
    const int nwaves = gridDim.x * (blockDim.x >> 6);

    float b1v[8], b2v[8];
    #pragma unroll
    for (int ct = 0; ct < 8; ++ct) {
        b1v[ct] = b1[ct * 16 + lrow];
        b2v[ct] = b2[ct * 16 + lrow];
    }

    const int ntiles = N_NODES / 16;
    for (int t = wave; t < ntiles; t += nwaves) {
        const int node = t * 16 + lrow;
        f32x4 acc1[8], acc2[8];
        #pragma unroll
        for (int ct = 0; ct < 8; ++ct) {
            acc1[ct] = (f32x4)(0.0f);
            acc2[ct] = (f32x4)(0.0f);
        }

        #pragma unroll
        for (int ks = 0; ks < 4; ++ks) {
            const int kk = ks * 32 + lgrp * 8;
            const f32x4* ep = (const f32x4*)(ego     + (size_t)node * DIM + kk);
            const f32x4* sp = (const f32x4*)(side_in + (size_t)node * DIM + kk);
            const f32x4 e0 = ep[0], e1 = ep[1];
            const f32x4 s0 = sp[0], s1 = sp[1];
            bf16x8 ax, ay;
            #pragma unroll
            for (int j = 0; j < 4; ++j) {
                ax[j]     = (__bf16)(e0[j] + s0[j]);
                ax[j + 4] = (__bf16)(e1[j] + s1[j]);
                ay[j]     = (__bf16)(e0[j] * s0[j]);
                ay[j + 4] = (__bf16)(e1[j] * s1[j]);
            }
            #pragma unroll
            for (int ct = 0; ct < 8; ++ct) {
                const int c = ct * 16 + lrow;
                const bf16x8 bv1 = *(const bf16x8*)&w1t[swz(c, kk)];
                const bf16x8 bv2 = *(const bf16x8*)&w2t[swz(c, kk)];
                acc1[ct] = __builtin_amdgcn_mfma_f32_16x16x32_bf16(ax, bv1, acc1[ct], 0, 0, 0);
                acc2[ct] = __builtin_amdgcn_mfma_f32_16x16x32_bf16(ay, bv2, acc2[ct], 0, 0, 0);
            }
        }

        const int orow_base = t * 16 + lgrp * 4;
        #pragma unroll
        for (int ct = 0; ct < 8; ++ct) {
            #pragma unroll
            for (int j = 0; j < 4; ++j) {
                float u = acc1[ct][j] + b1v[ct];
                float w = acc2[ct][j] + b2v[ct];
                u = (u > 0.0f) ? u : 0.01f * u;
                w = (w > 0.0f) ? w : 0.01f * w;
                out[(size_t)(orow_base + j) * DIM + ct * 16 + lrow] = u + w;
            }
        }
    }
}

extern "C" void kernel_launch(void* const* d_in, const int* in_sizes, int n_in,
                              void* d_out, int out_size, void* d_ws, size_t ws_size,
                              hipStream_t stream) {
    const int*   erow = (const int*)d_in[0];
    const int*   ecol = (const int*)d_in[1];
    const float* eval = (const float*)d_in[2];
    const float* ego  = (const float*)d_in[3];
    const float* W1   = (const float*)d_in[4];
    const float* b1   = (const float*)d_in[5];
    const float* W2   = (const float*)d_in[6];
    const float* b2   = (const float*)d_in[7];
    float* out = (float*)d_out;

    // workspace layout (256B-aligned slabs) — 156.5 MB total (proven fit)
    size_t off = 0;
    auto alloc = [&](size_t bytes) { size_t o = off; off = (off + bytes + 255) & ~(size_t)255; return o; };
    const size_t o_h2     = alloc((size_t)N2 * sizeof(int));
    const size_t o_s2     = alloc((size_t)N2 * sizeof(int));
    const size_t o_bsum   = alloc((size_t)SCAN_NBLK * sizeof(int));
    const size_t o_bpre   = alloc((size_t)SCAN_NBLK * sizeof(int));
    const size_t o_rp2    = alloc((size_t)NBUCK * 129 * sizeof(int));
    const size_t o_sorted = alloc((size_t)N_EDGES * sizeof(uint2));
    const size_t o_egob   = alloc((size_t)N_NODES * 64 * sizeof(unsigned int));
    const size_t need = off;

    if (ws_size >= need) {
        int*      h2     = (int*)((char*)d_ws + o_h2);
        int*      s2     = (int*)((char*)d_ws + o_s2);
        int*      bsum   = (int*)((char*)d_ws + o_bsum);
        int*      bpre   = (int*)((char*)d_ws + o_bpre);
        int*      rp2    = (int*)((char*)d_ws + o_rp2);
        uint2*    sorted = (uint2*)((char*)d_ws + o_sorted);
        unsigned* egob   = (unsigned*)((char*)d_ws + o_egob);

        cast_kernel   <<<4096, 256, 0, stream>>>(ego, egob);
        hist2d_kernel <<<BINWG, 256, 0, stream>>>(erow, h2);
        scan_reduce   <<<SCAN_NBLK, 256, 0, stream>>>(h2, bsum, N2);
        scan_top      <<<1, 1024, 0, stream>>>(bsum, bpre, SCAN_NBLK);
        scan_local    <<<SCAN_NBLK, 256, 0, stream>>>(h2, bpre, s2, N2);
        bin_kernel    <<<BINWG, 256, 0, stream>>>(erow, ecol, eval, s2, sorted);
        rowsort_kernel<<<NBUCK, 256, 0, stream>>>(s2, sorted, rp2);
        gather_kernel <<<4096, 256, 0, stream>>>(rp2, (const unsigned*)sorted, egob, out);
    } else {
        hipMemsetAsync(out, 0, (size_t)N_NODES * DIM * sizeof(float), stream);
        scatter_kernel<<<4096, 256, 0, stream>>>(erow, ecol, eval, ego, out);
    }
    dense_kernel<<<512, 256, 0, stream>>>(ego, out, W1, b1, W2, b2, out);
}